// Round 16
// baseline (50.206 us; speedup 1.0000x reference)
//
#include <hip/hip_runtime.h>

#define B_TOT 16384
#define NQ 7
#define H 64
#define MD 28

#define OIDX(hi,lo) ((hi)*((hi)-1)/2 + (lo))

__device__ __forceinline__ float fast_rcp(float x){ return __builtin_amdgcn_rcpf(x); }
__device__ __forceinline__ float sigmoid_f(float a){ return fast_rcp(1.0f + __expf(-a)); }
__device__ __forceinline__ float softplus_f(float a){ return fmaxf(a,0.0f) + __logf(1.0f + __expf(-fabsf(a))); }

// ---- parallel-order Jacobi helpers (verified R10/R11/R13) ----
#define JANGLE(i,P,Q) \
    float apq##i = Ao[OIDX(Q,P)]; \
    bool  rot##i = fabsf(apq##i) > 1e-20f; \
    float apqs##i = rot##i ? apq##i : 1.0f; \
    float th##i = (Ad[Q]-Ad[P]) * fast_rcp(2.0f*apqs##i); \
    float tt##i = fast_rcp(fabsf(th##i)+sqrtf(fmaf(th##i,th##i,1.0f))); \
    tt##i = (th##i<0.0f)? -tt##i : tt##i; \
    tt##i = rot##i ? tt##i : 0.0f; \
    float cc##i = rsqrtf(fmaf(tt##i,tt##i,1.0f)); \
    float ss##i = tt##i*cc##i;

#define JAPPLY(i,P,Q) \
    { \
        _Pragma("unroll") \
        for (int j=0;j<7;j++){ \
            if (j==P || j==Q) continue; \
            float ajp = (j<P)? Ao[OIDX(P,j)] : Ao[OIDX(j,P)]; \
            float ajq = (j<Q)? Ao[OIDX(Q,j)] : Ao[OIDX(j,Q)]; \
            float np_ = fmaf(cc##i,ajp,-ss##i*ajq); \
            float nq_ = fmaf(ss##i,ajp, cc##i*ajq); \
            if (j<P) Ao[OIDX(P,j)] = np_; else Ao[OIDX(j,P)] = np_; \
            if (j<Q) Ao[OIDX(Q,j)] = nq_; else Ao[OIDX(j,Q)] = nq_; \
        } \
        Ad[P] = fmaf(-tt##i,apq##i,Ad[P]); \
        Ad[Q] = fmaf( tt##i,apq##i,Ad[Q]); \
        Ao[OIDX(Q,P)] = 0.0f; \
        _Pragma("unroll") \
        for (int j=0;j<7;j++){ \
            float vp=V[j*7+P], vq=V[j*7+Q]; \
            V[j*7+P] = fmaf(cc##i,vp,-ss##i*vq); \
            V[j*7+Q] = fmaf(ss##i,vp, cc##i*vq); \
        } \
    }

#define JROUND(P0,Q0,P1,Q1,P2,Q2) \
    { JANGLE(0,P0,Q0) JANGLE(1,P1,Q1) JANGLE(2,P2,Q2) \
      JAPPLY(0,P0,Q0) JAPPLY(1,P1,Q1) JAPPLY(2,P2,Q2) }

#define SWEEP \
    JROUND(1,6, 2,5, 3,4) \
    JROUND(0,2, 3,6, 4,5) \
    JROUND(1,3, 0,4, 5,6) \
    JROUND(2,4, 1,5, 0,6) \
    JROUND(3,5, 2,6, 0,1) \
    JROUND(4,6, 0,3, 1,2) \
    JROUND(0,5, 1,4, 2,3)

// LDS layout (bytes)
// region A (phase scratch, aliased):
//   M:  zjz @0 (16384) | zjd @16384 (16384) | w1t @32768 (16384) | w2t @49152 (7168) = 56320
//   V:  zv0s @0 (16384) | s0sv @16384 (16384) | wv1t @32768 (16384)                  = 49152
//   D:  w2tk @0 (7168)  | rr1fs/red @7168 (16384)                                    = 23552
// persistent:
//   A0L @56320  A1L @72704  XL @89088  XDL @96256
//   SVL @103424 RPL @110592 MIL @112384 GRL @119552 (12544)  -> total 132096
#define SM_TOTAL 132096

__global__ __launch_bounds__(512,1) void k_fused(
    const float* __restrict__ q, const float* __restrict__ dq, const float* __restrict__ tau,
    const float* __restrict__ WM0, const float* __restrict__ bM0,
    const float* __restrict__ WM1, const float* __restrict__ bM1,
    const float* __restrict__ WM2, const float* __restrict__ bM2,
    const float* __restrict__ WV0, const float* __restrict__ bV0,
    const float* __restrict__ WV1, const float* __restrict__ bV1,
    const float* __restrict__ WV2,
    float* __restrict__ out)
{
    __shared__ __align__(16) char smem[SM_TOTAL];
    float*  zjz  = (float*)(smem);
    float*  zjd  = (float*)(smem+16384);
    float*  w1t  = (float*)(smem+32768);
    float*  w2t  = (float*)(smem+49152);
    float*  A0L  = (float*)(smem+56320);   // sigmoid(a0) [64][64]
    float*  A1L  = (float*)(smem+72704);   // sigmoid(a1) [64][64]
    float*  XL   = (float*)(smem+89088);   // [28][64]
    float*  XDL  = (float*)(smem+96256);   // [28][64]
    float*  SVL  = (float*)(smem+103424);  // [28][64]
    float*  RPL  = (float*)(smem+110592);  // [7][64]
    float*  MIL  = (float*)(smem+112384);  // [28][64]
    float*  GRL  = (float*)(smem+119552);  // [7 slices][7][64]

    const int tid=threadIdx.x, lane=tid&63, wid=tid>>6;
    const int e = blockIdx.x*64 + lane;

    float qv[NQ], dqv[NQ];
    #pragma unroll
    for (int d=0;d<NQ;d++){ qv[d]=q[e*NQ+d]; dqv[d]=dq[e*NQ+d]; }

    // ================= Phase M: M-net fwd + JVP =================
    for (int t=tid; t<H*H; t+=512)  w1t[(t&63)*H  + (t>>6)] = WM1[t];
    for (int t=tid; t<MD*H; t+=512) w2t[(t&63)*MD + (t>>6)] = WM2[t];

    #pragma unroll
    for (int oo=0;oo<8;oo++){
        const int o = wid*8+oo;
        float a=bM0[o], jd=0.f;
        #pragma unroll
        for (int d=0;d<NQ;d++){ float w=WM0[o*NQ+d]; a=fmaf(w,qv[d],a); jd=fmaf(w,dqv[d],jd); }
        float s0=sigmoid_f(a);
        A0L[o*64+lane]=s0;
        zjz[o*64+lane]=softplus_f(a);
        zjd[o*64+lane]=s0*jd;
    }
    __syncthreads();                                   // B1

    float a1[8], jd1[8];
    #pragma unroll
    for (int oo=0;oo<8;oo++){ a1[oo]=bM1[wid*8+oo]; jd1[oo]=0.f; }
    #pragma unroll 4
    for (int k=0;k<H;k++){
        float zx = zjz[k*64+lane];
        float zy = zjd[k*64+lane];
        float wv[8];
        *(float4*)&wv[0] = *(const float4*)&w1t[k*H + wid*8];
        *(float4*)&wv[4] = *(const float4*)&w1t[k*H + wid*8 + 4];
        #pragma unroll
        for (int oo=0;oo<8;oo++){ a1[oo]=fmaf(wv[oo],zx,a1[oo]); jd1[oo]=fmaf(wv[oo],zy,jd1[oo]); }
    }
    #pragma unroll
    for (int oo=0;oo<8;oo++) A1L[(wid*8+oo)*64+lane] = sigmoid_f(a1[oo]);
    __syncthreads();                                   // B2
    #pragma unroll
    for (int oo=0;oo<8;oo++){
        float s1=sigmoid_f(a1[oo]);
        zjz[(wid*8+oo)*64+lane]=softplus_f(a1[oo]);
        zjd[(wid*8+oo)*64+lane]=s1*jd1[oo];
    }
    __syncthreads();                                   // B3

    if (wid<7){
        float x[4], xd[4];
        #pragma unroll
        for (int mm=0;mm<4;mm++){ x[mm]=bM2[wid*4+mm]; xd[mm]=0.f; }
        #pragma unroll 4
        for (int k=0;k<H;k++){
            float zx = zjz[k*64+lane];
            float zy = zjd[k*64+lane];
            float wv[4];
            *(float4*)&wv[0] = *(const float4*)&w2t[k*MD + wid*4];
            #pragma unroll
            for (int mm=0;mm<4;mm++){ x[mm]=fmaf(wv[mm],zx,x[mm]); xd[mm]=fmaf(wv[mm],zy,xd[mm]); }
        }
        #pragma unroll
        for (int mm=0;mm<4;mm++){
            XL [(wid*4+mm)*64+lane]=x[mm];
            XDL[(wid*4+mm)*64+lane]=xd[mm];
        }
    }
    __syncthreads();                                   // B4

    // ================= Phase E/V: eigen (wave 0) || V-net (waves 1..7) =================
    if (wid==0){
        float x[MD], xd[MD];
        #pragma unroll
        for (int m=0;m<MD;m++){ x[m]=XL[m*64+lane]; xd[m]=XDL[m*64+lane]; }

        float Ad[NQ], Ao[21], V[49];
        #pragma unroll
        for (int i=0;i<NQ;i++) Ad[i]=x[i];
        #pragma unroll
        for (int t=0;t<21;t++) Ao[t]=x[NQ+t];
        #pragma unroll
        for (int t=0;t<49;t++) V[t]=0.0f;
        #pragma unroll
        for (int i=0;i<NQ;i++) V[i*7+i]=1.0f;

        #pragma unroll 1
        for (int sweep=0; sweep<2; sweep++){ SWEEP }
        __syncthreads();                               // B5 (matches vnet's post-L0)
        #pragma unroll 1
        for (int sweep=0; sweep<2; sweep++){ SWEEP }

        float ee[7], iee[7];
        #pragma unroll
        for (int i=0;i<7;i++){ ee[i]=__expf(Ad[i]); iee[i]=fast_rcp(ee[i]); }

        float Ro[21];
        #pragma unroll
        for (int p=0;p<6;p++){
            #pragma unroll
            for (int qj=p+1;qj<7;qj++){
                float d = Ad[p]-Ad[qj];
                bool big = fabsf(d) > 1e-3f;
                float den = big ? d : 1.0f;
                float exact = (ee[p]-ee[qj])*fast_rcp(den);
                float ser = sqrtf(ee[p]*ee[qj]) * fmaf(d*d,(1.0f/24.0f),1.0f);
                Ro[OIDX(qj,p)] = big ? exact : ser;
            }
        }

        float w[7];
        #pragma unroll
        for (int a=0;a<7;a++){
            float acc=0.0f;
            #pragma unroll
            for (int j=0;j<7;j++) acc=fmaf(V[j*7+a],dqv[j],acc);
            w[a]=acc;
        }

        {   // sv cotangent: S = V (R o wwT) V^T, offdiag doubled
            float Yd[7], Yo[21];
            #pragma unroll
            for (int a=0;a<7;a++) Yd[a]=ee[a]*w[a]*w[a];
            #pragma unroll
            for (int p=0;p<6;p++){
                #pragma unroll
                for (int qj=p+1;qj<7;qj++) Yo[OIDX(qj,p)]=Ro[OIDX(qj,p)]*w[p]*w[qj];
            }
            float P[49];
            #pragma unroll
            for (int i=0;i<7;i++){
                #pragma unroll
                for (int a=0;a<7;a++){
                    float acc=0.0f;
                    #pragma unroll
                    for (int c=0;c<7;c++){
                        float y=(c==a)? Yd[a] : ((c<a)? Yo[OIDX(a,c)] : Yo[OIDX(c,a)]);
                        acc=fmaf(V[i*7+c],y,acc);
                    }
                    P[i*7+a]=acc;
                }
            }
            #pragma unroll
            for (int i=0;i<7;i++){
                #pragma unroll
                for (int j=i;j<7;j++){
                    float acc=0.0f;
                    #pragma unroll
                    for (int a=0;a<7;a++) acc=fmaf(P[i*7+a],V[j*7+a],acc);
                    if (i==j) SVL[i*64+lane]=acc;
                    else      SVL[(NQ+OIDX(j,i))*64+lane]=2.0f*acc;
                }
            }
        }

        {   // rp = tau - Mdot*dq
            float P2[49];
            #pragma unroll
            for (int i=0;i<7;i++){
                #pragma unroll
                for (int a=0;a<7;a++){
                    float acc=0.0f;
                    #pragma unroll
                    for (int j=0;j<7;j++){
                        float u=(i==j)? xd[i] : ((j<i)? xd[NQ+OIDX(i,j)] : xd[NQ+OIDX(j,i)]);
                        acc=fmaf(u,V[j*7+a],acc);
                    }
                    P2[i*7+a]=acc;
                }
            }
            float Td[7], To[21];
            #pragma unroll
            for (int a=0;a<7;a++){
                float acc=0.0f;
                #pragma unroll
                for (int i=0;i<7;i++) acc=fmaf(V[i*7+a],P2[i*7+a],acc);
                Td[a]=acc;
            }
            #pragma unroll
            for (int a=0;a<6;a++){
                #pragma unroll
                for (int bb=a+1;bb<7;bb++){
                    float acc=0.0f;
                    #pragma unroll
                    for (int i=0;i<7;i++) acc=fmaf(V[i*7+a],P2[i*7+bb],acc);
                    To[OIDX(bb,a)]=acc;
                }
            }
            float zw[7];
            #pragma unroll
            for (int a=0;a<7;a++){
                float acc=ee[a]*Td[a]*w[a];
                #pragma unroll
                for (int bb=0;bb<7;bb++){
                    if (bb==a) continue;
                    float z=(bb<a)? (Ro[OIDX(a,bb)]*To[OIDX(a,bb)]) : (Ro[OIDX(bb,a)]*To[OIDX(bb,a)]);
                    acc=fmaf(z,w[bb],acc);
                }
                zw[a]=acc;
            }
            #pragma unroll
            for (int i=0;i<7;i++){
                float acc=0.0f;
                #pragma unroll
                for (int a=0;a<7;a++) acc=fmaf(V[i*7+a],zw[a],acc);
                RPL[i*64+lane] = tau[e*NQ+i]-acc;
            }
        }

        // Minv = V diag(1/ee) V^T
        #pragma unroll
        for (int i=0;i<7;i++){
            #pragma unroll
            for (int j=i;j<7;j++){
                float acc=0.0f;
                #pragma unroll
                for (int a=0;a<7;a++) acc=fmaf(V[i*7+a]*iee[a],V[j*7+a],acc);
                if (i==j) MIL[i*64+lane]=acc;
                else      MIL[(NQ+OIDX(j,i))*64+lane]=acc;
            }
        }
    } else {
        // ---------------- V-net on waves 1..7 (wave 7 covers slices 6 and 7) ----------------
        float* zv0s=(float*)(smem);
        float* s0sv=(float*)(smem+16384);
        float* wv1t=(float*)(smem+32768);

        for (int t=tid-64; t<H*H; t+=448) wv1t[(t&63)*H + (t>>6)] = WV1[t];

        const int nsl = (wid==7)? 2 : 1;
        #pragma unroll 1
        for (int s=0;s<nsl;s++){
            const int sl = s ? 7 : (wid-1);
            #pragma unroll
            for (int oo=0;oo<8;oo++){
                const int o=sl*8+oo;
                float a=bV0[o];
                #pragma unroll
                for (int d=0;d<NQ;d++) a=fmaf(WV0[o*NQ+d],qv[d],a);
                zv0s[o*64+lane]=softplus_f(a);
                s0sv[o*64+lane]=sigmoid_f(a);
            }
        }
        __syncthreads();                               // B5

        float racc[64];
        #pragma unroll
        for (int k=0;k<H;k++) racc[k]=0.f;
        #pragma unroll 1
        for (int s=0;s<nsl;s++){
            const int sl = s ? 7 : (wid-1);
            float av1[8];
            #pragma unroll
            for (int oo=0;oo<8;oo++) av1[oo]=bV1[sl*8+oo];
            #pragma unroll 4
            for (int k=0;k<H;k++){
                float zk = zv0s[k*64+lane];
                float wv[8];
                *(float4*)&wv[0] = *(const float4*)&wv1t[k*H + sl*8];
                *(float4*)&wv[4] = *(const float4*)&wv1t[k*H + sl*8 + 4];
                #pragma unroll
                for (int oo=0;oo<8;oo++) av1[oo]=fmaf(wv[oo],zk,av1[oo]);
            }
            float r1o[8];
            #pragma unroll
            for (int oo=0;oo<8;oo++) r1o[oo] = WV2[sl*8+oo]*sigmoid_f(av1[oo]);
            #pragma unroll
            for (int oo=0;oo<8;oo++){
                const int o=sl*8+oo;
                #pragma unroll
                for (int k=0;k<H;k++) racc[k]=fmaf(WV1[o*H+k],r1o[oo],racc[k]);
            }
        }
        float gp[NQ];
        #pragma unroll
        for (int d=0;d<NQ;d++) gp[d]=0.f;
        #pragma unroll
        for (int k=0;k<H;k++){
            float r0f = s0sv[k*64+lane]*racc[k];
            #pragma unroll
            for (int d=0;d<NQ;d++) gp[d]=fmaf(WV0[k*NQ+d],r0f,gp[d]);
        }
        #pragma unroll
        for (int d=0;d<NQ;d++) GRL[((wid-1)*NQ+d)*64+lane]=gp[d];
    }
    __syncthreads();                                   // B6

    // ================= Phase D: M-net reverse + rhs + solve =================
    float* w2tk  = (float*)(smem);
    float* rr1fs = (float*)(smem+7168);

    for (int t=tid;t<MD*H;t+=512) w2tk[(t&63)*MD+(t>>6)] = WM2[t];
    float sv[MD];
    #pragma unroll
    for (int m=0;m<MD;m++) sv[m]=SVL[m*64+lane];
    __syncthreads();                                   // B7

    #pragma unroll
    for (int kk=0;kk<8;kk++){
        const int k=wid*8+kk;
        float wv[MD];
        #pragma unroll
        for (int c=0;c<7;c++) *(float4*)&wv[c*4] = *(const float4*)&w2tk[k*MD + c*4];
        float acc=0.f;
        #pragma unroll
        for (int m=0;m<MD;m++) acc=fmaf(wv[m],sv[m],acc);
        rr1fs[k*64+lane] = A1L[k*64+lane]*acc;
    }
    __syncthreads();                                   // B8

    float u[64];
    #pragma unroll
    for (int k=0;k<H;k++) u[k]=0.f;
    #pragma unroll
    for (int ii=0;ii<8;ii++){
        const int i=wid*8+ii;
        float r=rr1fs[i*64+lane];
        #pragma unroll
        for (int k=0;k<H;k++) u[k]=fmaf(WM1[i*H+k],r,u[k]);
    }
    float sp[NQ];
    #pragma unroll
    for (int d=0;d<NQ;d++) sp[d]=0.f;
    #pragma unroll
    for (int k=0;k<H;k++){
        float t2=A0L[k*64+lane]*u[k];
        #pragma unroll
        for (int d=0;d<NQ;d++) sp[d]=fmaf(WM0[k*NQ+d],t2,sp[d]);
    }
    __syncthreads();                                   // B9 (before red-alias write)
    float* red = rr1fs;
    #pragma unroll
    for (int d=0;d<NQ;d++) red[(wid*NQ+d)*64+lane]=sp[d];
    __syncthreads();                                   // B10

    if (wid==0){
        #pragma unroll
        for (int w2=1;w2<8;w2++){
            #pragma unroll
            for (int d=0;d<NQ;d++) sp[d]+=red[(w2*NQ+d)*64+lane];
        }
        float g[NQ];
        #pragma unroll
        for (int d=0;d<NQ;d++){
            float acc=GRL[(0*NQ+d)*64+lane];
            #pragma unroll
            for (int w2=1;w2<7;w2++) acc+=GRL[(w2*NQ+d)*64+lane];
            g[d]=acc;
        }
        float rhs[NQ], mi[MD];
        #pragma unroll
        for (int d=0;d<NQ;d++)
            rhs[d] = RPL[d*64+lane] + 0.5f*sp[d] - g[d];
        #pragma unroll
        for (int t=0;t<MD;t++) mi[t]=MIL[t*64+lane];
        #pragma unroll
        for (int i=0;i<NQ;i++){
            float acc=0.0f;
            #pragma unroll
            for (int jj=0;jj<NQ;jj++){
                int idx=(jj==i)? i : (NQ + ((jj>i)? OIDX(jj,i) : OIDX(i,jj)));
                acc=fmaf(mi[idx],rhs[jj],acc);
            }
            out[e*NQ+i]=acc;
        }
    }
}

extern "C" void kernel_launch(void* const* d_in, const int* in_sizes, int n_in,
                              void* d_out, int out_size, void* d_ws, size_t ws_size,
                              hipStream_t stream) {
    const float* q   = (const float*)d_in[0];
    const float* dq  = (const float*)d_in[1];
    const float* tau = (const float*)d_in[2];
    const float* WM0 = (const float*)d_in[3];
    const float* bM0 = (const float*)d_in[4];
    const float* WM1 = (const float*)d_in[5];
    const float* bM1 = (const float*)d_in[6];
    const float* WM2 = (const float*)d_in[7];
    const float* bM2 = (const float*)d_in[8];
    const float* WV0 = (const float*)d_in[9];
    const float* bV0 = (const float*)d_in[10];
    const float* WV1 = (const float*)d_in[11];
    const float* bV1 = (const float*)d_in[12];
    const float* WV2 = (const float*)d_in[13];
    float* out = (float*)d_out;

    hipLaunchKernelGGL(k_fused, dim3(B_TOT/64), dim3(512), 0, stream,
                       q, dq, tau, WM0, bM0, WM1, bM1, WM2, bM2,
                       WV0, bV0, WV1, bV1, WV2, out);
}

// Round 17
// 45.922 us; speedup vs baseline: 1.0933x; 1.0933x over previous
//
#include <hip/hip_runtime.h>

#define B_TOT 16384
#define NQ 7
#define H 64
#define MD 28
#define W1S 68   // padded stride for transposed [k][o] weight tiles (17 float4s)

#define OIDX(hi,lo) ((hi)*((hi)-1)/2 + (lo))

__device__ __forceinline__ float fast_rcp(float x){ return __builtin_amdgcn_rcpf(x); }
__device__ __forceinline__ float sigmoid_f(float a){ return fast_rcp(1.0f + __expf(-a)); }
__device__ __forceinline__ float softplus_f(float a){ return fmaxf(a,0.0f) + __logf(1.0f + __expf(-fabsf(a))); }

// ---- parallel-order Jacobi helpers (verified R10/R11/R13) ----
#define JANGLE(i,P,Q) \
    float apq##i = Ao[OIDX(Q,P)]; \
    bool  rot##i = fabsf(apq##i) > 1e-20f; \
    float apqs##i = rot##i ? apq##i : 1.0f; \
    float th##i = (Ad[Q]-Ad[P]) * fast_rcp(2.0f*apqs##i); \
    float tt##i = fast_rcp(fabsf(th##i)+sqrtf(fmaf(th##i,th##i,1.0f))); \
    tt##i = (th##i<0.0f)? -tt##i : tt##i; \
    tt##i = rot##i ? tt##i : 0.0f; \
    float cc##i = rsqrtf(fmaf(tt##i,tt##i,1.0f)); \
    float ss##i = tt##i*cc##i;

#define JAPPLY(i,P,Q) \
    { \
        _Pragma("unroll") \
        for (int j=0;j<7;j++){ \
            if (j==P || j==Q) continue; \
            float ajp = (j<P)? Ao[OIDX(P,j)] : Ao[OIDX(j,P)]; \
            float ajq = (j<Q)? Ao[OIDX(Q,j)] : Ao[OIDX(j,Q)]; \
            float np_ = fmaf(cc##i,ajp,-ss##i*ajq); \
            float nq_ = fmaf(ss##i,ajp, cc##i*ajq); \
            if (j<P) Ao[OIDX(P,j)] = np_; else Ao[OIDX(j,P)] = np_; \
            if (j<Q) Ao[OIDX(Q,j)] = nq_; else Ao[OIDX(j,Q)] = nq_; \
        } \
        Ad[P] = fmaf(-tt##i,apq##i,Ad[P]); \
        Ad[Q] = fmaf( tt##i,apq##i,Ad[Q]); \
        Ao[OIDX(Q,P)] = 0.0f; \
        _Pragma("unroll") \
        for (int j=0;j<7;j++){ \
            float vp=V[j*7+P], vq=V[j*7+Q]; \
            V[j*7+P] = fmaf(cc##i,vp,-ss##i*vq); \
            V[j*7+Q] = fmaf(ss##i,vp, cc##i*vq); \
        } \
    }

#define JROUND(P0,Q0,P1,Q1,P2,Q2) \
    { JANGLE(0,P0,Q0) JANGLE(1,P1,Q1) JANGLE(2,P2,Q2) \
      JAPPLY(0,P0,Q0) JAPPLY(1,P1,Q1) JAPPLY(2,P2,Q2) }

#define SWEEP \
    JROUND(1,6, 2,5, 3,4) \
    JROUND(0,2, 3,6, 4,5) \
    JROUND(1,3, 0,4, 5,6) \
    JROUND(2,4, 1,5, 0,6) \
    JROUND(3,5, 2,6, 0,1) \
    JROUND(4,6, 0,3, 1,2) \
    JROUND(0,5, 1,4, 2,3)

// LDS layout (bytes)
// region A (phase scratch, aliased):
//   M:  zjz @0 (16384) | zjd @16384 (16384) | w1t @32768 (17408) | w2t @50176 (7168) = 57344
//   V:  zv0s @0 (16384) | s0sv @16384 (16384) | wv1t @32768 (17408, ends 50176)
//   D:  rr1fs/red @0 (16384) ; w2t @50176 reused from phase M
// persistent:
//   A0L @57344  A1L @73728  XL @90112  XDL @97280
//   SVL @104448 RPL @111616 MIL @113408 GRL @120576 (12544) -> total 133120
#define SM_TOTAL 133120

__global__ __launch_bounds__(512,1) void k_fused(
    const float* __restrict__ q, const float* __restrict__ dq, const float* __restrict__ tau,
    const float* __restrict__ WM0, const float* __restrict__ bM0,
    const float* __restrict__ WM1, const float* __restrict__ bM1,
    const float* __restrict__ WM2, const float* __restrict__ bM2,
    const float* __restrict__ WV0, const float* __restrict__ bV0,
    const float* __restrict__ WV1, const float* __restrict__ bV1,
    const float* __restrict__ WV2,
    float* __restrict__ out)
{
    __shared__ __align__(16) char smem[SM_TOTAL];
    float*  zjz  = (float*)(smem);
    float*  zjd  = (float*)(smem+16384);
    float*  w1t  = (float*)(smem+32768);   // [k][o] stride W1S
    float*  w2t  = (float*)(smem+50176);   // [k][m] stride MD (survives V phase)
    float*  A0L  = (float*)(smem+57344);   // sigmoid(a0) [64][64]
    float*  A1L  = (float*)(smem+73728);   // sigmoid(a1) [64][64]
    float*  XL   = (float*)(smem+90112);   // [28][64]
    float*  XDL  = (float*)(smem+97280);   // [28][64]
    float*  SVL  = (float*)(smem+104448);  // [28][64]
    float*  RPL  = (float*)(smem+111616);  // [7][64]
    float*  MIL  = (float*)(smem+113408);  // [28][64]
    float*  GRL  = (float*)(smem+120576);  // [7 slices][7][64]

    const int tid=threadIdx.x, lane=tid&63, wid=tid>>6;
    const int e = blockIdx.x*64 + lane;

    float qv[NQ], dqv[NQ];
    #pragma unroll
    for (int d=0;d<NQ;d++){ qv[d]=q[e*NQ+d]; dqv[d]=dq[e*NQ+d]; }

    // ================= Phase M: M-net fwd + JVP =================
    for (int t=tid; t<H*H; t+=512)  w1t[(t&63)*W1S + (t>>6)] = WM1[t];
    for (int t=tid; t<MD*H; t+=512) w2t[(t&63)*MD + (t>>6)] = WM2[t];

    #pragma unroll
    for (int oo=0;oo<8;oo++){
        const int o = wid*8+oo;
        float a=bM0[o], jd=0.f;
        #pragma unroll
        for (int d=0;d<NQ;d++){ float w=WM0[o*NQ+d]; a=fmaf(w,qv[d],a); jd=fmaf(w,dqv[d],jd); }
        float s0=sigmoid_f(a);
        A0L[o*64+lane]=s0;
        zjz[o*64+lane]=softplus_f(a);
        zjd[o*64+lane]=s0*jd;
    }
    __syncthreads();                                   // B1

    float a1[8], jd1[8];
    #pragma unroll
    for (int oo=0;oo<8;oo++){ a1[oo]=bM1[wid*8+oo]; jd1[oo]=0.f; }
    #pragma unroll 4
    for (int k=0;k<H;k++){
        float zx = zjz[k*64+lane];
        float zy = zjd[k*64+lane];
        float wv[8];
        *(float4*)&wv[0] = *(const float4*)&w1t[k*W1S + wid*8];
        *(float4*)&wv[4] = *(const float4*)&w1t[k*W1S + wid*8 + 4];
        #pragma unroll
        for (int oo=0;oo<8;oo++){ a1[oo]=fmaf(wv[oo],zx,a1[oo]); jd1[oo]=fmaf(wv[oo],zy,jd1[oo]); }
    }
    #pragma unroll
    for (int oo=0;oo<8;oo++) A1L[(wid*8+oo)*64+lane] = sigmoid_f(a1[oo]);
    __syncthreads();                                   // B2
    #pragma unroll
    for (int oo=0;oo<8;oo++){
        float s1=sigmoid_f(a1[oo]);
        zjz[(wid*8+oo)*64+lane]=softplus_f(a1[oo]);
        zjd[(wid*8+oo)*64+lane]=s1*jd1[oo];
    }
    __syncthreads();                                   // B3

    if (wid<7){
        float x[4], xd[4];
        #pragma unroll
        for (int mm=0;mm<4;mm++){ x[mm]=bM2[wid*4+mm]; xd[mm]=0.f; }
        #pragma unroll 4
        for (int k=0;k<H;k++){
            float zx = zjz[k*64+lane];
            float zy = zjd[k*64+lane];
            float wv[4];
            *(float4*)&wv[0] = *(const float4*)&w2t[k*MD + wid*4];
            #pragma unroll
            for (int mm=0;mm<4;mm++){ x[mm]=fmaf(wv[mm],zx,x[mm]); xd[mm]=fmaf(wv[mm],zy,xd[mm]); }
        }
        #pragma unroll
        for (int mm=0;mm<4;mm++){
            XL [(wid*4+mm)*64+lane]=x[mm];
            XDL[(wid*4+mm)*64+lane]=xd[mm];
        }
    }
    __syncthreads();                                   // B4

    // ================= Phase E/V: eigen (wave 0) || V-net (waves 1..7) =================
    if (wid==0){
        float x[MD], xd[MD];
        #pragma unroll
        for (int m=0;m<MD;m++){ x[m]=XL[m*64+lane]; xd[m]=XDL[m*64+lane]; }

        float Ad[NQ], Ao[21], V[49];
        #pragma unroll
        for (int i=0;i<NQ;i++) Ad[i]=x[i];
        #pragma unroll
        for (int t=0;t<21;t++) Ao[t]=x[NQ+t];
        #pragma unroll
        for (int t=0;t<49;t++) V[t]=0.0f;
        #pragma unroll
        for (int i=0;i<NQ;i++) V[i*7+i]=1.0f;

        #pragma unroll 1
        for (int sweep=0; sweep<2; sweep++){ SWEEP }
        __syncthreads();                               // B5 (matches vnet's post-L0)
        { SWEEP }                                      // third (final) sweep

        float ee[7], iee[7];
        #pragma unroll
        for (int i=0;i<7;i++){ ee[i]=__expf(Ad[i]); iee[i]=fast_rcp(ee[i]); }

        float Ro[21];
        #pragma unroll
        for (int p=0;p<6;p++){
            #pragma unroll
            for (int qj=p+1;qj<7;qj++){
                float d = Ad[p]-Ad[qj];
                bool big = fabsf(d) > 1e-3f;
                float den = big ? d : 1.0f;
                float exact = (ee[p]-ee[qj])*fast_rcp(den);
                float ser = sqrtf(ee[p]*ee[qj]) * fmaf(d*d,(1.0f/24.0f),1.0f);
                Ro[OIDX(qj,p)] = big ? exact : ser;
            }
        }

        float w[7];
        #pragma unroll
        for (int a=0;a<7;a++){
            float acc=0.0f;
            #pragma unroll
            for (int j=0;j<7;j++) acc=fmaf(V[j*7+a],dqv[j],acc);
            w[a]=acc;
        }

        {   // sv cotangent: S = V (R o wwT) V^T, offdiag doubled
            float Yd[7], Yo[21];
            #pragma unroll
            for (int a=0;a<7;a++) Yd[a]=ee[a]*w[a]*w[a];
            #pragma unroll
            for (int p=0;p<6;p++){
                #pragma unroll
                for (int qj=p+1;qj<7;qj++) Yo[OIDX(qj,p)]=Ro[OIDX(qj,p)]*w[p]*w[qj];
            }
            float P[49];
            #pragma unroll
            for (int i=0;i<7;i++){
                #pragma unroll
                for (int a=0;a<7;a++){
                    float acc=0.0f;
                    #pragma unroll
                    for (int c=0;c<7;c++){
                        float y=(c==a)? Yd[a] : ((c<a)? Yo[OIDX(a,c)] : Yo[OIDX(c,a)]);
                        acc=fmaf(V[i*7+c],y,acc);
                    }
                    P[i*7+a]=acc;
                }
            }
            #pragma unroll
            for (int i=0;i<7;i++){
                #pragma unroll
                for (int j=i;j<7;j++){
                    float acc=0.0f;
                    #pragma unroll
                    for (int a=0;a<7;a++) acc=fmaf(P[i*7+a],V[j*7+a],acc);
                    if (i==j) SVL[i*64+lane]=acc;
                    else      SVL[(NQ+OIDX(j,i))*64+lane]=2.0f*acc;
                }
            }
        }

        {   // rp = tau - Mdot*dq
            float P2[49];
            #pragma unroll
            for (int i=0;i<7;i++){
                #pragma unroll
                for (int a=0;a<7;a++){
                    float acc=0.0f;
                    #pragma unroll
                    for (int j=0;j<7;j++){
                        float u=(i==j)? xd[i] : ((j<i)? xd[NQ+OIDX(i,j)] : xd[NQ+OIDX(j,i)]);
                        acc=fmaf(u,V[j*7+a],acc);
                    }
                    P2[i*7+a]=acc;
                }
            }
            float Td[7], To[21];
            #pragma unroll
            for (int a=0;a<7;a++){
                float acc=0.0f;
                #pragma unroll
                for (int i=0;i<7;i++) acc=fmaf(V[i*7+a],P2[i*7+a],acc);
                Td[a]=acc;
            }
            #pragma unroll
            for (int a=0;a<6;a++){
                #pragma unroll
                for (int bb=a+1;bb<7;bb++){
                    float acc=0.0f;
                    #pragma unroll
                    for (int i=0;i<7;i++) acc=fmaf(V[i*7+a],P2[i*7+bb],acc);
                    To[OIDX(bb,a)]=acc;
                }
            }
            float zw[7];
            #pragma unroll
            for (int a=0;a<7;a++){
                float acc=ee[a]*Td[a]*w[a];
                #pragma unroll
                for (int bb=0;bb<7;bb++){
                    if (bb==a) continue;
                    float z=(bb<a)? (Ro[OIDX(a,bb)]*To[OIDX(a,bb)]) : (Ro[OIDX(bb,a)]*To[OIDX(bb,a)]);
                    acc=fmaf(z,w[bb],acc);
                }
                zw[a]=acc;
            }
            #pragma unroll
            for (int i=0;i<7;i++){
                float acc=0.0f;
                #pragma unroll
                for (int a=0;a<7;a++) acc=fmaf(V[i*7+a],zw[a],acc);
                RPL[i*64+lane] = tau[e*NQ+i]-acc;
            }
        }

        // Minv = V diag(1/ee) V^T
        #pragma unroll
        for (int i=0;i<7;i++){
            #pragma unroll
            for (int j=i;j<7;j++){
                float acc=0.0f;
                #pragma unroll
                for (int a=0;a<7;a++) acc=fmaf(V[i*7+a]*iee[a],V[j*7+a],acc);
                if (i==j) MIL[i*64+lane]=acc;
                else      MIL[(NQ+OIDX(j,i))*64+lane]=acc;
            }
        }
    } else {
        // ---------------- V-net on waves 1..7 (wave 7 covers slices 6 and 7) ----------------
        float* zv0s=(float*)(smem);
        float* s0sv=(float*)(smem+16384);
        float* wv1t=(float*)(smem+32768);   // [k][o] stride W1S

        for (int t=tid-64; t<H*H; t+=448) wv1t[(t&63)*W1S + (t>>6)] = WV1[t];

        const int nsl = (wid==7)? 2 : 1;
        #pragma unroll 1
        for (int s=0;s<nsl;s++){
            const int sl = s ? 7 : (wid-1);
            #pragma unroll
            for (int oo=0;oo<8;oo++){
                const int o=sl*8+oo;
                float a=bV0[o];
                #pragma unroll
                for (int d=0;d<NQ;d++) a=fmaf(WV0[o*NQ+d],qv[d],a);
                zv0s[o*64+lane]=softplus_f(a);
                s0sv[o*64+lane]=sigmoid_f(a);
            }
        }
        __syncthreads();                               // B5

        float racc[64];
        #pragma unroll
        for (int k=0;k<H;k++) racc[k]=0.f;
        #pragma unroll 1
        for (int s=0;s<nsl;s++){
            const int sl = s ? 7 : (wid-1);
            float av1[8];
            #pragma unroll
            for (int oo=0;oo<8;oo++) av1[oo]=bV1[sl*8+oo];
            #pragma unroll 4
            for (int k=0;k<H;k++){
                float zk = zv0s[k*64+lane];
                float wv[8];
                *(float4*)&wv[0] = *(const float4*)&wv1t[k*W1S + sl*8];
                *(float4*)&wv[4] = *(const float4*)&wv1t[k*W1S + sl*8 + 4];
                #pragma unroll
                for (int oo=0;oo<8;oo++) av1[oo]=fmaf(wv[oo],zk,av1[oo]);
            }
            float r1o[8];
            #pragma unroll
            for (int oo=0;oo<8;oo++) r1o[oo] = WV2[sl*8+oo]*sigmoid_f(av1[oo]);
            #pragma unroll
            for (int oo=0;oo<8;oo++){
                const int o=sl*8+oo;
                #pragma unroll
                for (int k=0;k<H;k++) racc[k]=fmaf(WV1[o*H+k],r1o[oo],racc[k]);
            }
        }
        float gp[NQ];
        #pragma unroll
        for (int d=0;d<NQ;d++) gp[d]=0.f;
        #pragma unroll
        for (int k=0;k<H;k++){
            float r0f = s0sv[k*64+lane]*racc[k];
            #pragma unroll
            for (int d=0;d<NQ;d++) gp[d]=fmaf(WV0[k*NQ+d],r0f,gp[d]);
        }
        #pragma unroll
        for (int d=0;d<NQ;d++) GRL[((wid-1)*NQ+d)*64+lane]=gp[d];
    }
    __syncthreads();                                   // B6

    // ================= Phase D: M-net reverse + rhs + solve =================
    float* rr1fs = (float*)(smem);       // clobbers V-phase scratch (done)

    float sv[MD];
    #pragma unroll
    for (int m=0;m<MD;m++) sv[m]=SVL[m*64+lane];

    #pragma unroll
    for (int kk=0;kk<8;kk++){
        const int k=wid*8+kk;
        float wv[MD];
        #pragma unroll
        for (int c=0;c<7;c++) *(float4*)&wv[c*4] = *(const float4*)&w2t[k*MD + c*4];
        float acc=0.f;
        #pragma unroll
        for (int m=0;m<MD;m++) acc=fmaf(wv[m],sv[m],acc);
        rr1fs[k*64+lane] = A1L[k*64+lane]*acc;
    }
    __syncthreads();                                   // B7

    float u[64];
    #pragma unroll
    for (int k=0;k<H;k++) u[k]=0.f;
    #pragma unroll
    for (int ii=0;ii<8;ii++){
        const int i=wid*8+ii;
        float r=rr1fs[i*64+lane];
        #pragma unroll
        for (int k=0;k<H;k++) u[k]=fmaf(WM1[i*H+k],r,u[k]);
    }
    float sp[NQ];
    #pragma unroll
    for (int d=0;d<NQ;d++) sp[d]=0.f;
    #pragma unroll
    for (int k=0;k<H;k++){
        float t2=A0L[k*64+lane]*u[k];
        #pragma unroll
        for (int d=0;d<NQ;d++) sp[d]=fmaf(WM0[k*NQ+d],t2,sp[d]);
    }
    __syncthreads();                                   // B8 (before red-alias write)
    float* red = rr1fs;
    #pragma unroll
    for (int d=0;d<NQ;d++) red[(wid*NQ+d)*64+lane]=sp[d];
    __syncthreads();                                   // B9

    if (wid==0){
        #pragma unroll
        for (int w2=1;w2<8;w2++){
            #pragma unroll
            for (int d=0;d<NQ;d++) sp[d]+=red[(w2*NQ+d)*64+lane];
        }
        float g[NQ];
        #pragma unroll
        for (int d=0;d<NQ;d++){
            float acc=GRL[(0*NQ+d)*64+lane];
            #pragma unroll
            for (int w2=1;w2<7;w2++) acc+=GRL[(w2*NQ+d)*64+lane];
            g[d]=acc;
        }
        float rhs[NQ], mi[MD];
        #pragma unroll
        for (int d=0;d<NQ;d++)
            rhs[d] = RPL[d*64+lane] + 0.5f*sp[d] - g[d];
        #pragma unroll
        for (int t=0;t<MD;t++) mi[t]=MIL[t*64+lane];
        #pragma unroll
        for (int i=0;i<NQ;i++){
            float acc=0.0f;
            #pragma unroll
            for (int jj=0;jj<NQ;jj++){
                int idx=(jj==i)? i : (NQ + ((jj>i)? OIDX(jj,i) : OIDX(i,jj)));
                acc=fmaf(mi[idx],rhs[jj],acc);
            }
            out[e*NQ+i]=acc;
        }
    }
}

extern "C" void kernel_launch(void* const* d_in, const int* in_sizes, int n_in,
                              void* d_out, int out_size, void* d_ws, size_t ws_size,
                              hipStream_t stream) {
    const float* q   = (const float*)d_in[0];
    const float* dq  = (const float*)d_in[1];
    const float* tau = (const float*)d_in[2];
    const float* WM0 = (const float*)d_in[3];
    const float* bM0 = (const float*)d_in[4];
    const float* WM1 = (const float*)d_in[5];
    const float* bM1 = (const float*)d_in[6];
    const float* WM2 = (const float*)d_in[7];
    const float* bM2 = (const float*)d_in[8];
    const float* WV0 = (const float*)d_in[9];
    const float* bV0 = (const float*)d_in[10];
    const float* WV1 = (const float*)d_in[11];
    const float* bV1 = (const float*)d_in[12];
    const float* WV2 = (const float*)d_in[13];
    float* out = (float*)d_out;

    hipLaunchKernelGGL(k_fused, dim3(B_TOT/64), dim3(512), 0, stream,
                       q, dq, tau, WM0, bM0, WM1, bM1, WM2, bM2,
                       WV0, bV0, WV1, bV1, WV2, out);
}